// Round 1
// baseline (22866.316 us; speedup 1.0000x reference)
//
#include <hip/hip_runtime.h>
#include <hip/hip_bf16.h>
#include <math.h>

#define TT 1024
#define DD 768
#define HH 12
#define HDD 64
#define LL 6
#define DFF 3072
#define VV 32000

// ---------------- reductions (wave = 64 on gfx950) ----------------
__device__ __forceinline__ float wave_sum(float v) {
#pragma unroll
  for (int o = 32; o > 0; o >>= 1) v += __shfl_down(v, o, 64);
  return v;
}
__device__ __forceinline__ float wave_max(float v) {
#pragma unroll
  for (int o = 32; o > 0; o >>= 1) v = fmaxf(v, __shfl_down(v, o, 64));
  return v;
}
// block of 256 threads = 4 waves. buf must hold >=4 floats.
__device__ __forceinline__ float block_sum256(float v, float* buf) {
  v = wave_sum(v);
  int lane = threadIdx.x & 63, w = threadIdx.x >> 6;
  if (lane == 0) buf[w] = v;
  __syncthreads();
  float r = buf[0] + buf[1] + buf[2] + buf[3];
  __syncthreads();
  return r;
}
__device__ __forceinline__ float block_max256(float v, float* buf) {
  v = wave_max(v);
  int lane = threadIdx.x & 63, w = threadIdx.x >> 6;
  if (lane == 0) buf[w] = v;
  __syncthreads();
  float r = fmaxf(fmaxf(buf[0], buf[1]), fmaxf(buf[2], buf[3]));
  __syncthreads();
  return r;
}

// ---------------- embedding: x[r,:] = tok_emb[idx[r],:] + pos_emb[r%T,:] ----
__global__ __launch_bounds__(256) void embed_kernel(const int* __restrict__ idx,
    const float* __restrict__ tok, const float* __restrict__ pos,
    float* __restrict__ x) {
  int r = blockIdx.x;          // 0..B*T-1, b-major
  int t = r & (TT - 1);
  int tokid = idx[r];
  const float* tp = tok + (size_t)tokid * DD;
  const float* pp = pos + (size_t)t * DD;
  float* xp = x + (size_t)r * DD;
#pragma unroll
  for (int i = 0; i < 3; ++i) {
    int c = threadIdx.x + i * 256;
    xp[c] = tp[c] + pp[c];
  }
}

// ---------------- LayerNorm: one block per row, D=768 -----------------------
__global__ __launch_bounds__(256) void ln_kernel(const float* __restrict__ x,
    const float* __restrict__ g, const float* __restrict__ b,
    float* __restrict__ y) {
  __shared__ float buf[4];
  int r = blockIdx.x;
  const float* xp = x + (size_t)r * DD;
  float vals[3];
  float s = 0.f;
#pragma unroll
  for (int i = 0; i < 3; ++i) { vals[i] = xp[threadIdx.x + i * 256]; s += vals[i]; }
  float mu = block_sum256(s, buf) * (1.f / DD);
  float vs = 0.f;
#pragma unroll
  for (int i = 0; i < 3; ++i) { float d = vals[i] - mu; vs += d * d; }
  float var = block_sum256(vs, buf) * (1.f / DD);
  float inv = rsqrtf(var + 1e-5f);
  float* yp = y + (size_t)r * DD;
#pragma unroll
  for (int i = 0; i < 3; ++i) {
    int c = threadIdx.x + i * 256;
    yp[c] = (vals[i] - mu) * inv * g[c] + b[c];
  }
}

// ---------------- tiled fp32 GEMM: C = [res +] act(A@B + bias) --------------
// A [M,K] row-major, B [K,N] row-major, M given by gridDim.y*64.
// 64x64 tile, BK=16, 256 threads, 4x4 micro-tile per thread.
template<bool GELU, bool RES>
__global__ __launch_bounds__(256) void gemm_kernel(const float* __restrict__ A,
    const float* __restrict__ B, const float* __restrict__ bias,
    const float* __restrict__ res, float* __restrict__ C, int N, int K) {
  constexpr int BM = 64, BN = 64, BK = 16;
  __shared__ float As[BK][BM + 1];   // [k][m], padded to dodge 4-way store conflict
  __shared__ float Bs[BK][BN];       // [k][n]
  int tid = threadIdx.x;
  int tx = tid & 15, ty = tid >> 4;
  int row0 = blockIdx.y * BM;
  int col0 = blockIdx.x * BN;
  float acc[4][4] = {};
  // A loader: m = tid/4, kk0 = (tid%4)*4   (float4 along K; K%16==0 so aligned)
  int am = tid >> 2;
  int ak = (tid & 3) << 2;
  // B loader: kk = tid/16, n0 = (tid%16)*4 (float4 along N; N%64==0 so aligned)
  int bk = tid >> 4;
  int bn = (tid & 15) << 2;
  for (int k0 = 0; k0 < K; k0 += BK) {
    float4 av = *(const float4*)(A + (size_t)(row0 + am) * K + k0 + ak);
    As[ak + 0][am] = av.x; As[ak + 1][am] = av.y;
    As[ak + 2][am] = av.z; As[ak + 3][am] = av.w;
    float4 bv = *(const float4*)(B + (size_t)(k0 + bk) * N + col0 + bn);
    *(float4*)&Bs[bk][bn] = bv;
    __syncthreads();
#pragma unroll
    for (int kk = 0; kk < BK; ++kk) {
      float a[4], b[4];
#pragma unroll
      for (int i = 0; i < 4; ++i) a[i] = As[kk][ty * 4 + i];
#pragma unroll
      for (int j = 0; j < 4; ++j) b[j] = Bs[kk][tx * 4 + j];
#pragma unroll
      for (int i = 0; i < 4; ++i)
#pragma unroll
        for (int j = 0; j < 4; ++j)
          acc[i][j] = fmaf(a[i], b[j], acc[i][j]);
    }
    __syncthreads();
  }
#pragma unroll
  for (int i = 0; i < 4; ++i) {
    int r = row0 + ty * 4 + i;
#pragma unroll
    for (int j = 0; j < 4; ++j) {
      int c = col0 + tx * 4 + j;
      float v = acc[i][j];
      if (bias) v += bias[c];
      if (GELU) v = 0.5f * v * (1.f + erff(v * 0.70710678118654752f));
      if (RES) v += res[(size_t)r * N + c];
      C[(size_t)r * N + c] = v;
    }
  }
}

// ---------------- attention: one block per (b,h,t) query row ----------------
// q,k,v laid out [B*T, D] with head h at columns h*64..h*64+63.
__global__ __launch_bounds__(256) void attn_kernel(const float* __restrict__ q,
    const float* __restrict__ k, const float* __restrict__ v,
    float* __restrict__ o) {
  __shared__ float qs[HDD];
  __shared__ float sc[TT];
  __shared__ float buf[4];
  __shared__ float ored[4][HDD];
  int t = blockIdx.x, h = blockIdx.y, b = blockIdx.z;
  int tid = threadIdx.x;
  int n = t + 1;                       // causal: keys 0..t
  const float scale = 0.125f;          // 64^-0.5
  const float* qp = q + ((size_t)(b * TT + t)) * DD + h * HDD;
  if (tid < HDD) qs[tid] = qp[tid] * scale;
  __syncthreads();
  for (int j = tid; j < n; j += 256) {
    const float* kp = k + ((size_t)(b * TT + j)) * DD + h * HDD;
    float s = 0.f;
#pragma unroll
    for (int d = 0; d < HDD; ++d) s = fmaf(qs[d], kp[d], s);
    sc[j] = s;
  }
  __syncthreads();
  float m = -3.0e38f;
  for (int j = tid; j < n; j += 256) m = fmaxf(m, sc[j]);
  m = block_max256(m, buf);
  float s = 0.f;
  for (int j = tid; j < n; j += 256) { float p = expf(sc[j] - m); sc[j] = p; s += p; }
  float denom = block_sum256(s, buf);  // barrier inside also publishes sc[]
  int d = tid & 63, qtr = tid >> 6;
  float acc = 0.f;
  for (int j = qtr; j < n; j += 4)
    acc = fmaf(sc[j], v[((size_t)(b * TT + j)) * DD + h * HDD + d], acc);
  ored[qtr][d] = acc;
  __syncthreads();
  if (tid < HDD) {
    float r = (ored[0][tid] + ored[1][tid] + ored[2][tid] + ored[3][tid]) / denom;
    o[((size_t)(b * TT + t)) * DD + h * HDD + tid] = r;
  }
}

// ---------------- orchestration ---------------------------------------------
extern "C" void kernel_launch(void* const* d_in, const int* in_sizes, int n_in,
                              void* d_out, int out_size, void* d_ws, size_t ws_size,
                              hipStream_t stream) {
  const int Bc = 4, M = Bc * TT;       // 4096 rows
  const int* idx   = (const int*)d_in[0];
  const float* tok = (const float*)d_in[1];
  const float* pos = (const float*)d_in[2];
  const float* Wq  = (const float*)d_in[3];
  const float* Wk  = (const float*)d_in[4];
  const float* Wv  = (const float*)d_in[5];
  const float* Wo  = (const float*)d_in[6];
  const float* bo  = (const float*)d_in[7];
  const float* W1  = (const float*)d_in[8];
  const float* b1  = (const float*)d_in[9];
  const float* W2  = (const float*)d_in[10];
  const float* b2  = (const float*)d_in[11];
  const float* ln1g = (const float*)d_in[12];
  const float* ln1b = (const float*)d_in[13];
  const float* ln2g = (const float*)d_in[14];
  const float* ln2b = (const float*)d_in[15];
  const float* lnfg = (const float*)d_in[16];
  const float* lnfb = (const float*)d_in[17];
  const float* hW  = (const float*)d_in[18];
  const float* hb  = (const float*)d_in[19];
  float* out = (float*)d_out;

  // workspace layout (floats): x, h, then q|k|v|o (the q..o span is reused as
  // the [M,DFF] FF intermediate — 4*D == DFF so it fits exactly).
  float* x  = (float*)d_ws;
  float* h  = x  + (size_t)M * DD;
  float* qb = h  + (size_t)M * DD;
  float* kb = qb + (size_t)M * DD;
  float* vb = kb + (size_t)M * DD;
  float* ob = vb + (size_t)M * DD;
  float* f1 = qb;                      // [M, DFF] alias over q|k|v|o

  dim3 blk(256);
  dim3 gD(DD / 64, M / 64);            // N=768 tiles
  dim3 gF(DFF / 64, M / 64);           // N=3072 tiles
  dim3 gV(VV / 64, M / 64);            // N=32000 tiles

  embed_kernel<<<M, blk, 0, stream>>>(idx, tok, pos, x);
  for (int l = 0; l < LL; ++l) {
    ln_kernel<<<M, blk, 0, stream>>>(x, ln1g + l * DD, ln1b + l * DD, h);
    gemm_kernel<false, false><<<gD, blk, 0, stream>>>(h, Wq + (size_t)l * DD * DD, nullptr, nullptr, qb, DD, DD);
    gemm_kernel<false, false><<<gD, blk, 0, stream>>>(h, Wk + (size_t)l * DD * DD, nullptr, nullptr, kb, DD, DD);
    gemm_kernel<false, false><<<gD, blk, 0, stream>>>(h, Wv + (size_t)l * DD * DD, nullptr, nullptr, vb, DD, DD);
    attn_kernel<<<dim3(TT, HH, Bc), blk, 0, stream>>>(qb, kb, vb, ob);
    gemm_kernel<false, true><<<gD, blk, 0, stream>>>(ob, Wo + (size_t)l * DD * DD, bo + l * DD, x, x, DD, DD);
    ln_kernel<<<M, blk, 0, stream>>>(x, ln2g + l * DD, ln2b + l * DD, h);
    gemm_kernel<true, false><<<gF, blk, 0, stream>>>(h, W1 + (size_t)l * DD * DFF, b1 + l * DFF, nullptr, f1, DFF, DD);
    gemm_kernel<false, true><<<gD, blk, 0, stream>>>(f1, W2 + (size_t)l * DFF * DD, b2 + l * DD, x, x, DD, DFF);
  }
  ln_kernel<<<M, blk, 0, stream>>>(x, lnfg, lnfb, h);
  gemm_kernel<false, false><<<gV, blk, 0, stream>>>(h, hW, hb, nullptr, out, VV, DD);
}